// Round 19
// baseline (481.581 us; speedup 1.0000x reference)
//
#include <hip/hip_runtime.h>
#include <math.h>

// ---------------------------------------------------------------------------
// AttnModel3: B=256, N=64, F=64, S=130.
//   q_f(n) = ( U_f + c_f(n)*W[129,:] - m_f(n)*A_f ) * inv_f(n) + B_f
// R19 = R18 (single-phase pipeline, 1 barrier/n, register operands, fp16)
//   + qb/kb row stride 168->172 shorts (86 dwords, 22 mod 32 -> 16 distinct
//     bank-slots for the 16 l15-lanes; kills the 8-way QK ds_read conflicts)
//   + k0/k1 merged into one 263-block kernel (independent outputs).
// ---------------------------------------------------------------------------

typedef __attribute__((ext_vector_type(4))) float f32x4;
typedef __attribute__((ext_vector_type(8))) _Float16 h8;

#define EPSF 1e-6f
#define INVS 0.0877058019307029f /* 1/sqrt(130) */
#define QKS 172  /* qb/kb row stride in shorts */

__device__ __forceinline__ unsigned short f2h(float f) {
  _Float16 h = (_Float16)f;
  return __builtin_bit_cast(unsigned short, h);
}
__device__ __forceinline__ float h2f(unsigned short s) {
  return (float)__builtin_bit_cast(_Float16, s);
}
__device__ __forceinline__ unsigned int pkh(float a, float b) {
  unsigned int r;
  asm("v_cvt_pkrtz_f16_f32 %0, %1, %2" : "=v"(r) : "v"(a), "v"(b));
  return r;
}

// ---------------- kernel 01: merged precomputes ----------------
// blocks 0..255: per-b U (fp16) + S1/S2   blocks 256..262: global A/B/AW/Pa/Cc
__global__ __launch_bounds__(256) void k01(
    const float* __restrict__ h1, const float* __restrict__ h2,
    const float* __restrict__ sp,
    const float* __restrict__ alpha1, const float* __restrict__ beta1,
    const float* __restrict__ alpha2, const float* __restrict__ beta2,
    const float* __restrict__ Wq, const float* __restrict__ bq,
    const float* __restrict__ Wk, const float* __restrict__ bk,
    const float* __restrict__ Wv, const float* __restrict__ bv,
    const float* __restrict__ Wlin, const float* __restrict__ blin,
    unsigned short* __restrict__ UqkB, unsigned short* __restrict__ UvB,
    unsigned short* __restrict__ ABqk, unsigned short* __restrict__ ABv,
    unsigned short* __restrict__ AWt, float* __restrict__ Paw, float* __restrict__ Ccw,
    float* __restrict__ S1g, float* __restrict__ S2g)
{
  __shared__ float gbuf[64 * 132];
  __shared__ float Wbuf[130 * 144];
  __shared__ float ps[2][256];
  int bx = blockIdx.x, tid = threadIdx.x;

  if (bx < 256) {
    // ---------------- k1 body: per-b U, S1, S2 ----------------
    int b = bx;
    float s1 = 0.f, s2 = 0.f;
    for (int idx = tid; idx < 8256; idx += 256) {  // 129*64
      int s = idx >> 6, f = idx & 63;
      float x = (s < 64)  ? h1[((size_t)(b * 64 + s)) * 64 + f]
              : (s < 128) ? h2[((size_t)(b * 64 + (s - 64))) * 64 + f]
                          : sp[b * 64 + f];
      gbuf[f * 132 + s] = alpha1[f * 130 + s] * x;
      s1 += x; s2 += x * x;
    }
    ps[0][tid] = s1; ps[1][tid] = s2;
    __syncthreads();
    if (tid < 64) {
      S1g[b * 64 + tid] = ps[0][tid] + ps[0][tid + 64] + ps[0][tid + 128] + ps[0][tid + 192];
      S2g[b * 64 + tid] = ps[1][tid] + ps[1][tid + 64] + ps[1][tid + 128] + ps[1][tid + 192];
    }
    int ty = tid >> 4, tx = tid & 15;
    for (int m = 0; m < 3; ++m) {
      const float* W = (m == 0) ? Wq : (m == 1) ? Wk : Wv;
      __syncthreads();
      for (int e = tid; e < 16900; e += 256) { int s = e / 130, t = e - s * 130; Wbuf[s * 144 + t] = W[e]; }
      __syncthreads();
      float acc[4][9] = {};
      for (int s = 0; s < 129; ++s) {  // K = 129 (col 129 handled per-n)
        float g0 = gbuf[(ty * 4 + 0) * 132 + s];
        float g1 = gbuf[(ty * 4 + 1) * 132 + s];
        float g2 = gbuf[(ty * 4 + 2) * 132 + s];
        float g3 = gbuf[(ty * 4 + 3) * 132 + s];
#pragma unroll
        for (int c = 0; c < 9; ++c) {
          float wv = Wbuf[s * 144 + tx + 16 * c];
          acc[0][c] += g0 * wv; acc[1][c] += g1 * wv;
          acc[2][c] += g2 * wv; acc[3][c] += g3 * wv;
        }
      }
#pragma unroll
      for (int i = 0; i < 4; ++i)
        for (int c = 0; c < 9; ++c) {
          int t = tx + 16 * c;
          if (t < 136) {
            unsigned short v16 = f2h((t < 130) ? acc[i][c] : 0.f);
            int f = ty * 4 + i;
            if (m == 2) UvB[((size_t)b * 136 + t) * 64 + f] = v16;               // [t][f]
            else        UqkB[(((size_t)b * 2 + m) * 64 + f) * 136 + t] = v16;    // [f][t]
          }
        }
    }
  } else {
    // ---------------- k0 body: global precomputes ----------------
    int blk = bx - 256;
    if (blk < 6) {
      int m = blk >> 1, isB = blk & 1;
      const float* src  = isB ? beta1 : alpha1;
      const float* W    = (m == 0) ? Wq : (m == 1) ? Wk : Wv;
      const float* bias = (m == 0) ? bq : (m == 1) ? bk : bv;
      for (int e = tid; e < 8320; e += 256) { int f = e / 130, s = e - f * 130; gbuf[f * 132 + s] = src[e]; }
      for (int e = tid; e < 16900; e += 256) { int s = e / 130, t = e - s * 130; Wbuf[s * 144 + t] = W[e]; }
      __syncthreads();
      int ty = tid >> 4, tx = tid & 15;
      float acc[4][9] = {};
      for (int s = 0; s < 130; ++s) {
        float g0 = gbuf[(ty * 4 + 0) * 132 + s];
        float g1 = gbuf[(ty * 4 + 1) * 132 + s];
        float g2 = gbuf[(ty * 4 + 2) * 132 + s];
        float g3 = gbuf[(ty * 4 + 3) * 132 + s];
#pragma unroll
        for (int c = 0; c < 9; ++c) {
          float wv = Wbuf[s * 144 + tx + 16 * c];
          acc[0][c] += g0 * wv; acc[1][c] += g1 * wv;
          acc[2][c] += g2 * wv; acc[3][c] += g3 * wv;
        }
      }
#pragma unroll
      for (int i = 0; i < 4; ++i)
        for (int c = 0; c < 9; ++c) {
          int t = tx + 16 * c;
          if (t < 136) {
            float val = (t < 130) ? (acc[i][c] + (isB ? bias[t] : 0.f)) : 0.f;
            unsigned short v16 = f2h(val);
            int f = ty * 4 + i;
            if (m == 2) ABv[t * 128 + isB * 64 + f] = v16;                       // [t][{A,B}][f]
            else        ABqk[(m * 64 + f) * 272 + (t >> 3) * 16 + isB * 8 + (t & 7)] = v16;
          }
        }
    } else {  // blk == 6
      if (tid < 64) {
        int f = tid;
        float pa = 0.f, cc = 0.f;
        for (int s = 0; s < 130; ++s) {
          float wl = Wlin[f * 130 + s];
          float aw = alpha2[f * 130 + s] * wl;
          AWt[s * 72 + f] = f2h(aw);   // transposed [col][row]
          pa += aw;
          cc += beta2[f * 130 + s] * wl;
        }
        for (int s = 130; s < 144; ++s) AWt[s * 72 + f] = 0;
        Paw[f] = pa;
#pragma unroll
        for (int msk = 1; msk <= 32; msk <<= 1) cc += __shfl_xor(cc, msk, 64);
        if (f == 0) Ccw[0] = cc + blin[0];
      }
    }
  }
}

// ---------------- kernel 2: single-phase pipeline, 1 barrier/n ----------------
__global__ __launch_bounds__(512, 2) void k2(
    const float* __restrict__ h2, const float* __restrict__ alpha1,
    const unsigned short* __restrict__ UqkB, const unsigned short* __restrict__ UvB,
    const unsigned short* __restrict__ ABqk, const unsigned short* __restrict__ ABv,
    const unsigned short* __restrict__ AWt,
    const float* __restrict__ S1g, const float* __restrict__ S2g,
    const float* __restrict__ Paw, const float* __restrict__ Ccw,
    const float* __restrict__ Wq, const float* __restrict__ Wk, const float* __restrict__ Wv,
    float* __restrict__ out)
{
  __shared__ __align__(16) unsigned short qb[2][64 * QKS];   // 44032 B
  __shared__ __align__(16) unsigned short kb[2][64 * QKS];   // 44032 B
  __shared__ __align__(16) unsigned short vT[2][144 * 72];   // 41472 B
  __shared__ __align__(16) unsigned short pb[64 * 72];       //  9216 B
  __shared__ __align__(16) unsigned short w129h[3][136];     //   816 B
  __shared__ float S1l[64], S2l[64], ael[64];
  __shared__ __align__(16) unsigned short mrowB[2][64], irowB[2][64], crowB[2][64];
  __shared__ float redbuf[2][4];
  // total ~141 KB; 1 block/CU, 8 waves (2/SIMD)

  int b = blockIdx.x, tid = threadIdx.x;
  int w = tid >> 6, l = tid & 63, l15 = l & 15, l4 = l >> 4;

  // ---- one-time init ----
  if (tid < 136) {
    w129h[0][tid] = (tid < 130) ? f2h(Wq[129 * 130 + tid]) : (unsigned short)0;
    w129h[1][tid] = (tid < 130) ? f2h(Wk[129 * 130 + tid]) : (unsigned short)0;
    w129h[2][tid] = (tid < 130) ? f2h(Wv[129 * 130 + tid]) : (unsigned short)0;
  }
  if (tid >= 192 && tid < 256) {   // S1/S2/ael
    int ff = tid - 192;
    S1l[ff] = S1g[b * 64 + ff];
    S2l[ff] = S2g[b * 64 + ff];
    ael[ff] = alpha1[ff * 130 + 129];
  }
  if (tid < 128) {                 // coeffs for n=0 (slot 0), n=1 (slot 1)
    int nn = tid >> 6, ff = tid & 63;
    float a  = h2[((size_t)(b * 64 + nn)) * 64 + ff];
    float s1 = S1g[b * 64 + ff], s2 = S2g[b * 64 + ff];
    float m  = (s1 + a) * (1.f / 130.f);
    float e2 = (s2 + a * a) * (1.f / 130.f);
    float sd = sqrtf(fmaxf(e2 - m * m, 0.f));
    mrowB[nn][ff] = f2h(m);
    irowB[nn][ff] = f2h(1.f / (sd + EPSF));
    crowB[nn][ff] = f2h(alpha1[ff * 130 + 129] * a);
  }
  for (int i = tid; i < 2 * 64 * 24; i += 512) {   // zero K-tails both buffers
    int c = i / (64 * 24), j = i - c * (64 * 24);
    int ff = j / 24, t = 136 + (j - ff * 24);
    qb[c][ff * QKS + t] = 0; kb[c][ff * QKS + t] = 0;
  }
  for (int i = tid; i < 2 * 14 * 72; i += 512) {   // zero vT pad rows both buffers
    int c = i / (14 * 72), j = i - c * (14 * 72);
    vT[c][130 * 72 + j] = 0;
  }

  // ---- compute-wave register hoists ----
  float awr[9][4], pawr[4];
  if (w < 4) {
#pragma unroll
    for (int sf = 0; sf < 9; ++sf)
#pragma unroll
      for (int rr = 0; rr < 4; ++rr)
        awr[sf][rr] = h2f(AWt[(sf * 16 + l15) * 72 + w * 16 + l4 * 4 + rr]);
#pragma unroll
    for (int rr = 0; rr < 4; ++rr) pawr[rr] = Paw[w * 16 + l4 * 4 + rr];
  }
  float ccv = Ccw[0];

  // ---- regen operand register preloads (n-invariant; R15/R17-proven) ----
  int isK = tid >> 8, t5 = tid & 255;
  const unsigned short* uqkg = UqkB + ((size_t)b * 2 + isK) * 64 * 136;
  const unsigned short* abg  = ABqk + isK * 64 * 272;
  const unsigned short* uvg  = UvB + (size_t)b * 136 * 64;

  auto ldu = [&](int o) { int fo = o / 17, g = o - fo * 17;
                          return *(const h8*)(uqkg + fo * 136 + g * 8); };
  auto lda = [&](int o) { int fo = o / 17, g = o - fo * 17;
                          return *(const h8*)(abg + fo * 272 + g * 16); };
  auto ldb = [&](int o) { int fo = o / 17, g = o - fo * 17;
                          return *(const h8*)(abg + fo * 272 + g * 16 + 8); };
  h8 qU0 = ldu(t5),       qA0 = lda(t5),       qB0 = ldb(t5);
  h8 qU1 = ldu(t5 + 256), qA1 = lda(t5 + 256), qB1 = ldb(t5 + 256);
  h8 qU2 = ldu(t5 + 512), qA2 = lda(t5 + 512), qB2 = ldb(t5 + 512);
  h8 qU3 = ldu(t5 + 768), qA3 = lda(t5 + 768), qB3 = ldb(t5 + 768);
  h8 qUt = {}, qAt = {}, qBt = {};
  if (t5 < 64) { qUt = ldu(1024 + t5); qAt = lda(1024 + t5); qBt = ldb(1024 + t5); }
  auto ldvu = [&](int o) { int t = o >> 3, vf = o & 7;
                           return *(const h8*)(uvg + t * 64 + vf * 8); };
  auto ldva = [&](int o) { int t = o >> 3, vf = o & 7;
                           return *(const h8*)(ABv + t * 128 + vf * 8); };
  auto ldvb = [&](int o) { int t = o >> 3, vf = o & 7;
                           return *(const h8*)(ABv + t * 128 + 64 + vf * 8); };
  h8 vU0 = ldvu(tid),       vA0 = ldva(tid),       vB0 = ldvb(tid);
  h8 vU1 = ldvu(tid + 512), vA1 = ldva(tid + 512), vB1 = ldvb(tid + 512);
  h8 vUt = {}, vAt = {}, vBt = {};
  if (tid < 16) { vUt = ldvu(1024 + tid); vAt = ldva(1024 + tid); vBt = ldvb(1024 + tid); }

  __syncthreads();   // coeffs slots 0/1, w129h, tails, S1l ready

  // regen one q/k octet (register operands) into buffer with coeff slot sl
  auto genqk = [&](int o, h8 uu, h8 aa, h8 bb, int sl, unsigned short* dstb) {
    int fo = o / 17, g = o - fo * 17;
    _Float16 m   = __builtin_bit_cast(_Float16, mrowB[sl][fo]);
    _Float16 inv = __builtin_bit_cast(_Float16, irowB[sl][fo]);
    _Float16 c   = __builtin_bit_cast(_Float16, crowB[sl][fo]);
    h8 ww = *(const h8*)(&w129h[isK][g * 8]);
    h8 res = (uu + c * ww - m * aa) * inv + bb;
    *(h8*)(dstb + fo * QKS + g * 8) = res;
  };
  auto genv = [&](int o, h8 uu, h8 aa, h8 bb, int sl, unsigned short* vbase) {
    int t = o >> 3, vf = o & 7;
    _Float16 wv = __builtin_bit_cast(_Float16, w129h[2][t]);
    h8 mv = *(const h8*)(&mrowB[sl][vf * 8]);
    h8 iv = *(const h8*)(&irowB[sl][vf * 8]);
    h8 cv = *(const h8*)(&crowB[sl][vf * 8]);
    h8 res = (uu + cv * wv - mv * aa) * iv + bb;
    *(h8*)(vbase + t * 72 + vf * 8) = res;
  };
  auto regen_all = [&](int bufi, int sl) {
    unsigned short* dq = isK ? kb[bufi] : qb[bufi];
    genqk(t5,       qU0, qA0, qB0, sl, dq);
    genqk(t5 + 256, qU1, qA1, qB1, sl, dq);
    genqk(t5 + 512, qU2, qA2, qB2, sl, dq);
    genqk(t5 + 768, qU3, qA3, qB3, sl, dq);
    if (t5 < 64) genqk(1024 + t5, qUt, qAt, qBt, sl, dq);
    genv(tid,       vU0, vA0, vB0, sl, vT[bufi]);
    genv(tid + 512, vU1, vA1, vB1, sl, vT[bufi]);
    if (tid < 16) genv(1024 + tid, vUt, vAt, vBt, sl, vT[bufi]);
  };

  // ---- prologue: regen n=0 into buf[0] (slot 0) ----
  regen_all(0, 0);
  __syncthreads();

  // ---- main loop: ONE barrier per n ----
  for (int n = 0; n < 64; ++n) {
    int p = n & 1;
    if (n > 0 && tid == 0)
      out[b * 64 + n - 1] = redbuf[1 - p][0] + redbuf[1 - p][1]
                          + redbuf[1 - p][2] + redbuf[1 - p][3] + ccv;
    // regen n+1 into buf[1-p] (all waves; independent of compute below)
    if (n < 63) regen_all(1 - p, 1 - p);

    if (w < 4) {
      // ======== COMPUTE n from buf[p] (in-wave) ========
      const unsigned short* qbp = qb[p];
      const unsigned short* kbp = kb[p];
      const unsigned short* vtp = vT[p];
      f32x4 sacc[4] = {};
      {
        const unsigned short* qrow = &qbp[(w * 16 + l15) * QKS + l4 * 8];
#pragma unroll
        for (int kk = 0; kk < 5; ++kk) {
          h8 avv = *(const h8*)&qrow[kk * 32];
#pragma unroll
          for (int cf = 0; cf < 4; ++cf) {
            h8 bvv = *(const h8*)&kbp[(cf * 16 + l15) * QKS + l4 * 8 + kk * 32];
            sacc[cf] = __builtin_amdgcn_mfma_f32_16x16x32_f16(avv, bvv, sacc[cf], 0, 0, 0);
          }
        }
      }
      // max-free in-wave softmax (|sim*INVS| << 88; shift-invariant)
      float prob[4][4];
#pragma unroll
      for (int rr = 0; rr < 4; ++rr) {
        float ssum = 0.f;
#pragma unroll
        for (int cf = 0; cf < 4; ++cf) {
          float e = __expf(sacc[cf][rr] * INVS);
          prob[cf][rr] = e;
          ssum += e;
        }
#pragma unroll
        for (int msk = 1; msk <= 8; msk <<= 1) ssum += __shfl_xor(ssum, msk, 64);
        float is = 1.f / ssum;
#pragma unroll
        for (int cf = 0; cf < 4; ++cf) prob[cf][rr] *= is;
      }
#pragma unroll
      for (int cf = 0; cf < 4; ++cf) {
        unsigned int p01 = pkh(prob[cf][0], prob[cf][1]);
        unsigned int p23 = pkh(prob[cf][2], prob[cf][3]);
        int base = (w * 16 + l4 * 4) * 72 + cf * 16 + l15;
        pb[base]       = (unsigned short)p01;
        pb[base + 72]  = (unsigned short)(p01 >> 16);
        pb[base + 144] = (unsigned short)p23;
        pb[base + 216] = (unsigned short)(p23 >> 16);
      }
      // pb rows produced and consumed by the same wave (R1-proven).

      // PV: all 9 s-tiles in-wave
      f32x4 ao[9] = {};
      {
        const unsigned short* prow = &pb[(w * 16 + l15) * 72 + l4 * 8];
#pragma unroll
        for (int kk = 0; kk < 2; ++kk) {
          h8 avv = *(const h8*)&prow[kk * 32];
#pragma unroll
          for (int sf = 0; sf < 9; ++sf) {
            h8 bvv = *(const h8*)&vtp[(sf * 16 + l15) * 72 + l4 * 8 + kk * 32];
            ao[sf] = __builtin_amdgcn_mfma_f32_16x16x32_f16(avv, bvv, ao[sf], 0, 0, 0);
          }
        }
      }
      // in-wave stats + projection (register AW; pads are zero)
      float csum = 0.f;
#pragma unroll
      for (int rr = 0; rr < 4; ++rr) {
        float s1 = 0.f, s2 = 0.f, sdt = 0.f;
#pragma unroll
        for (int sf = 0; sf < 9; ++sf) {
          float v = ao[sf][rr];
          s1 += v; s2 += v * v; sdt += v * awr[sf][rr];
        }
#pragma unroll
        for (int msk = 1; msk <= 8; msk <<= 1) {
          s1 += __shfl_xor(s1, msk, 64);
          s2 += __shfl_xor(s2, msk, 64);
          sdt += __shfl_xor(sdt, msk, 64);
        }
        float mz  = 2.f * s1 * (1.f / 130.f);
        float ez2 = 4.f * s2 * (1.f / 130.f);
        float sg  = sqrtf(fmaxf(ez2 - mz * mz, 0.f));
        float i2  = 1.f / (sg + EPSF);
        csum += (2.f * sdt - mz * pawr[rr]) * i2;
      }
      csum += __shfl_xor(csum, 16, 64);
      csum += __shfl_xor(csum, 32, 64);
      if (l == 0) redbuf[p][w] = csum;
    } else if (w == 4 && n < 62) {
      // coeffs for n+2 -> slot p (regen this phase reads slot 1-p)
      int ff = l;
      float a  = h2[((size_t)(b * 64 + n + 2)) * 64 + ff];
      float m  = (S1l[ff] + a) * (1.f / 130.f);
      float e2 = (S2l[ff] + a * a) * (1.f / 130.f);
      float sd = sqrtf(fmaxf(e2 - m * m, 0.f));
      mrowB[p][ff] = f2h(m);
      irowB[p][ff] = f2h(1.f / (sd + EPSF));
      crowB[p][ff] = f2h(ael[ff] * a);
    }
    __syncthreads();
  }
  if (tid == 0)
    out[b * 64 + 63] = redbuf[1][0] + redbuf[1][1] + redbuf[1][2] + redbuf[1][3] + ccv;
}

// ---------------- host launch ----------------
extern "C" void kernel_launch(void* const* d_in, const int* in_sizes, int n_in,
                              void* d_out, int out_size, void* d_ws, size_t ws_size,
                              hipStream_t stream) {
  const float* sp     = (const float*)d_in[0];
  const float* h1     = (const float*)d_in[1];
  const float* h2     = (const float*)d_in[2];
  const float* Wq     = (const float*)d_in[3];
  const float* bq     = (const float*)d_in[4];
  const float* Wk     = (const float*)d_in[5];
  const float* bk     = (const float*)d_in[6];
  const float* Wv     = (const float*)d_in[7];
  const float* bv     = (const float*)d_in[8];
  const float* alpha1 = (const float*)d_in[9];
  const float* beta1  = (const float*)d_in[10];
  const float* alpha2 = (const float*)d_in[11];
  const float* beta2  = (const float*)d_in[12];
  const float* Wlin   = (const float*)d_in[13];
  const float* blin   = (const float*)d_in[14];
  float* out = (float*)d_out;

  unsigned short* UqkB = (unsigned short*)d_ws;     // 256*2*64*136 = 4,456,448
  unsigned short* UvB  = UqkB + 4456448;            // 256*136*64   = 2,228,224
  unsigned short* ABqk = UvB + 2228224;             // 2*64*272     = 34,816
  unsigned short* ABv  = ABqk + 34816;              // 136*128      = 17,408
  unsigned short* AWt  = ABv + 17408;               // 144*72       = 10,368
  float* S1g = (float*)(AWt + 10368);               // 16384
  float* S2g = S1g + 16384;                         // 16384
  float* Paw = S2g + 16384;                         // 64
  float* Ccw = Paw + 64;                            // 1   -> total ~13.6 MB

  k01<<<dim3(263), dim3(256), 0, stream>>>(h1, h2, sp,
                                           alpha1, beta1, alpha2, beta2,
                                           Wq, bq, Wk, bk, Wv, bv, Wlin, blin,
                                           UqkB, UvB, ABqk, ABv, AWt, Paw, Ccw,
                                           S1g, S2g);
  k2<<<dim3(256), dim3(512), 0, stream>>>(h2, alpha1, UqkB, UvB, ABqk, ABv, AWt,
                                          S1g, S2g, Paw, Ccw,
                                          Wq, Wk, Wv, out);
}

// Round 20
// 309.532 us; speedup vs baseline: 1.5558x; 1.5558x over previous
//
#include <hip/hip_runtime.h>
#include <math.h>

// ---------------------------------------------------------------------------
// AttnModel3: B=256, N=64, F=64, S=130.
//   q_f(n) = ( U_f + c_f(n)*W[129,:] - m_f(n)*A_f ) * inv_f(n) + B_f
// R20 = R18 k2 verbatim (single-phase pipeline, 1 barrier/n, register
// operands, fp16, stride 168 = 16B-aligned) + merged k01 precompute kernel
// (R19's orthogonal good half). R19's stride-172 was 8B-misaligned -> split
// b128 LDS ops -> regression; reverted.
// ---------------------------------------------------------------------------

typedef __attribute__((ext_vector_type(4))) float f32x4;
typedef __attribute__((ext_vector_type(8))) _Float16 h8;

#define EPSF 1e-6f
#define INVS 0.0877058019307029f /* 1/sqrt(130) */

__device__ __forceinline__ unsigned short f2h(float f) {
  _Float16 h = (_Float16)f;
  return __builtin_bit_cast(unsigned short, h);
}
__device__ __forceinline__ float h2f(unsigned short s) {
  return (float)__builtin_bit_cast(_Float16, s);
}
__device__ __forceinline__ unsigned int pkh(float a, float b) {
  unsigned int r;
  asm("v_cvt_pkrtz_f16_f32 %0, %1, %2" : "=v"(r) : "v"(a), "v"(b));
  return r;
}

// ---------------- kernel 01: merged precomputes ----------------
// blocks 0..255: per-b U (fp16) + S1/S2   blocks 256..262: global A/B/AW/Pa/Cc
__global__ __launch_bounds__(256) void k01(
    const float* __restrict__ h1, const float* __restrict__ h2,
    const float* __restrict__ sp,
    const float* __restrict__ alpha1, const float* __restrict__ beta1,
    const float* __restrict__ alpha2, const float* __restrict__ beta2,
    const float* __restrict__ Wq, const float* __restrict__ bq,
    const float* __restrict__ Wk, const float* __restrict__ bk,
    const float* __restrict__ Wv, const float* __restrict__ bv,
    const float* __restrict__ Wlin, const float* __restrict__ blin,
    unsigned short* __restrict__ UqkB, unsigned short* __restrict__ UvB,
    unsigned short* __restrict__ ABqk, unsigned short* __restrict__ ABv,
    unsigned short* __restrict__ AWt, float* __restrict__ Paw, float* __restrict__ Ccw,
    float* __restrict__ S1g, float* __restrict__ S2g)
{
  __shared__ float gbuf[64 * 132];
  __shared__ float Wbuf[130 * 144];
  __shared__ float ps[2][256];
  int bx = blockIdx.x, tid = threadIdx.x;

  if (bx < 256) {
    // ---------------- per-b U, S1, S2 ----------------
    int b = bx;
    float s1 = 0.f, s2 = 0.f;
    for (int idx = tid; idx < 8256; idx += 256) {  // 129*64
      int s = idx >> 6, f = idx & 63;
      float x = (s < 64)  ? h1[((size_t)(b * 64 + s)) * 64 + f]
              : (s < 128) ? h2[((size_t)(b * 64 + (s - 64))) * 64 + f]
                          : sp[b * 64 + f];
      gbuf[f * 132 + s] = alpha1[f * 130 + s] * x;
      s1 += x; s2 += x * x;
    }
    ps[0][tid] = s1; ps[1][tid] = s2;
    __syncthreads();
    if (tid < 64) {
      S1g[b * 64 + tid] = ps[0][tid] + ps[0][tid + 64] + ps[0][tid + 128] + ps[0][tid + 192];
      S2g[b * 64 + tid] = ps[1][tid] + ps[1][tid + 64] + ps[1][tid + 128] + ps[1][tid + 192];
    }
    int ty = tid >> 4, tx = tid & 15;
    for (int m = 0; m < 3; ++m) {
      const float* W = (m == 0) ? Wq : (m == 1) ? Wk : Wv;
      __syncthreads();
      for (int e = tid; e < 16900; e += 256) { int s = e / 130, t = e - s * 130; Wbuf[s * 144 + t] = W[e]; }
      __syncthreads();
      float acc[4][9] = {};
      for (int s = 0; s < 129; ++s) {  // K = 129 (col 129 handled per-n)
        float g0 = gbuf[(ty * 4 + 0) * 132 + s];
        float g1 = gbuf[(ty * 4 + 1) * 132 + s];
        float g2 = gbuf[(ty * 4 + 2) * 132 + s];
        float g3 = gbuf[(ty * 4 + 3) * 132 + s];
#pragma unroll
        for (int c = 0; c < 9; ++c) {
          float wv = Wbuf[s * 144 + tx + 16 * c];
          acc[0][c] += g0 * wv; acc[1][c] += g1 * wv;
          acc[2][c] += g2 * wv; acc[3][c] += g3 * wv;
        }
      }
#pragma unroll
      for (int i = 0; i < 4; ++i)
        for (int c = 0; c < 9; ++c) {
          int t = tx + 16 * c;
          if (t < 136) {
            unsigned short v16 = f2h((t < 130) ? acc[i][c] : 0.f);
            int f = ty * 4 + i;
            if (m == 2) UvB[((size_t)b * 136 + t) * 64 + f] = v16;               // [t][f]
            else        UqkB[(((size_t)b * 2 + m) * 64 + f) * 136 + t] = v16;    // [f][t]
          }
        }
    }
  } else {
    // ---------------- global precomputes ----------------
    int blk = bx - 256;
    if (blk < 6) {
      int m = blk >> 1, isB = blk & 1;
      const float* src  = isB ? beta1 : alpha1;
      const float* W    = (m == 0) ? Wq : (m == 1) ? Wk : Wv;
      const float* bias = (m == 0) ? bq : (m == 1) ? bk : bv;
      for (int e = tid; e < 8320; e += 256) { int f = e / 130, s = e - f * 130; gbuf[f * 132 + s] = src[e]; }
      for (int e = tid; e < 16900; e += 256) { int s = e / 130, t = e - s * 130; Wbuf[s * 144 + t] = W[e]; }
      __syncthreads();
      int ty = tid >> 4, tx = tid & 15;
      float acc[4][9] = {};
      for (int s = 0; s < 130; ++s) {
        float g0 = gbuf[(ty * 4 + 0) * 132 + s];
        float g1 = gbuf[(ty * 4 + 1) * 132 + s];
        float g2 = gbuf[(ty * 4 + 2) * 132 + s];
        float g3 = gbuf[(ty * 4 + 3) * 132 + s];
#pragma unroll
        for (int c = 0; c < 9; ++c) {
          float wv = Wbuf[s * 144 + tx + 16 * c];
          acc[0][c] += g0 * wv; acc[1][c] += g1 * wv;
          acc[2][c] += g2 * wv; acc[3][c] += g3 * wv;
        }
      }
#pragma unroll
      for (int i = 0; i < 4; ++i)
        for (int c = 0; c < 9; ++c) {
          int t = tx + 16 * c;
          if (t < 136) {
            float val = (t < 130) ? (acc[i][c] + (isB ? bias[t] : 0.f)) : 0.f;
            unsigned short v16 = f2h(val);
            int f = ty * 4 + i;
            if (m == 2) ABv[t * 128 + isB * 64 + f] = v16;                       // [t][{A,B}][f]
            else        ABqk[(m * 64 + f) * 272 + (t >> 3) * 16 + isB * 8 + (t & 7)] = v16;
          }
        }
    } else {  // blk == 6
      if (tid < 64) {
        int f = tid;
        float pa = 0.f, cc = 0.f;
        for (int s = 0; s < 130; ++s) {
          float wl = Wlin[f * 130 + s];
          float aw = alpha2[f * 130 + s] * wl;
          AWt[s * 72 + f] = f2h(aw);   // transposed [col][row]
          pa += aw;
          cc += beta2[f * 130 + s] * wl;
        }
        for (int s = 130; s < 144; ++s) AWt[s * 72 + f] = 0;
        Paw[f] = pa;
#pragma unroll
        for (int msk = 1; msk <= 32; msk <<= 1) cc += __shfl_xor(cc, msk, 64);
        if (f == 0) Ccw[0] = cc + blin[0];
      }
    }
  }
}

// ---------------- kernel 2: single-phase pipeline, 1 barrier/n ----------------
__global__ __launch_bounds__(512, 2) void k2(
    const float* __restrict__ h2, const float* __restrict__ alpha1,
    const unsigned short* __restrict__ UqkB, const unsigned short* __restrict__ UvB,
    const unsigned short* __restrict__ ABqk, const unsigned short* __restrict__ ABv,
    const unsigned short* __restrict__ AWt,
    const float* __restrict__ S1g, const float* __restrict__ S2g,
    const float* __restrict__ Paw, const float* __restrict__ Ccw,
    const float* __restrict__ Wq, const float* __restrict__ Wk, const float* __restrict__ Wv,
    float* __restrict__ out)
{
  __shared__ __align__(16) unsigned short qb[2][64 * 168];   // 43008 B
  __shared__ __align__(16) unsigned short kb[2][64 * 168];   // 43008 B
  __shared__ __align__(16) unsigned short vT[2][144 * 72];   // 41472 B
  __shared__ __align__(16) unsigned short pb[64 * 72];       //  9216 B
  __shared__ __align__(16) unsigned short w129h[3][136];     //   816 B
  __shared__ float S1l[64], S2l[64], ael[64];
  __shared__ __align__(16) unsigned short mrowB[2][64], irowB[2][64], crowB[2][64];
  __shared__ float redbuf[2][4];
  // total ~139 KB; 1 block/CU, 8 waves (2/SIMD)

  int b = blockIdx.x, tid = threadIdx.x;
  int w = tid >> 6, l = tid & 63, l15 = l & 15, l4 = l >> 4;

  // ---- one-time init ----
  if (tid < 136) {
    w129h[0][tid] = (tid < 130) ? f2h(Wq[129 * 130 + tid]) : (unsigned short)0;
    w129h[1][tid] = (tid < 130) ? f2h(Wk[129 * 130 + tid]) : (unsigned short)0;
    w129h[2][tid] = (tid < 130) ? f2h(Wv[129 * 130 + tid]) : (unsigned short)0;
  }
  if (tid >= 192 && tid < 256) {   // S1/S2/ael
    int ff = tid - 192;
    S1l[ff] = S1g[b * 64 + ff];
    S2l[ff] = S2g[b * 64 + ff];
    ael[ff] = alpha1[ff * 130 + 129];
  }
  if (tid < 128) {                 // coeffs for n=0 (slot 0), n=1 (slot 1)
    int nn = tid >> 6, ff = tid & 63;
    float a  = h2[((size_t)(b * 64 + nn)) * 64 + ff];
    float s1 = S1g[b * 64 + ff], s2 = S2g[b * 64 + ff];
    float m  = (s1 + a) * (1.f / 130.f);
    float e2 = (s2 + a * a) * (1.f / 130.f);
    float sd = sqrtf(fmaxf(e2 - m * m, 0.f));
    mrowB[nn][ff] = f2h(m);
    irowB[nn][ff] = f2h(1.f / (sd + EPSF));
    crowB[nn][ff] = f2h(alpha1[ff * 130 + 129] * a);
  }
  for (int i = tid; i < 2 * 64 * 24; i += 512) {   // zero K-tails both buffers
    int c = i / (64 * 24), j = i - c * (64 * 24);
    int ff = j / 24, t = 136 + (j - ff * 24);
    qb[c][ff * 168 + t] = 0; kb[c][ff * 168 + t] = 0;
  }
  for (int i = tid; i < 2 * 14 * 72; i += 512) {   // zero vT pad rows both buffers
    int c = i / (14 * 72), j = i - c * (14 * 72);
    vT[c][130 * 72 + j] = 0;
  }

  // ---- compute-wave register hoists ----
  float awr[9][4], pawr[4];
  if (w < 4) {
#pragma unroll
    for (int sf = 0; sf < 9; ++sf)
#pragma unroll
      for (int rr = 0; rr < 4; ++rr)
        awr[sf][rr] = h2f(AWt[(sf * 16 + l15) * 72 + w * 16 + l4 * 4 + rr]);
#pragma unroll
    for (int rr = 0; rr < 4; ++rr) pawr[rr] = Paw[w * 16 + l4 * 4 + rr];
  }
  float ccv = Ccw[0];

  // ---- regen operand register preloads (n-invariant; R15/R17-proven) ----
  int isK = tid >> 8, t5 = tid & 255;
  const unsigned short* uqkg = UqkB + ((size_t)b * 2 + isK) * 64 * 136;
  const unsigned short* abg  = ABqk + isK * 64 * 272;
  const unsigned short* uvg  = UvB + (size_t)b * 136 * 64;

  auto ldu = [&](int o) { int fo = o / 17, g = o - fo * 17;
                          return *(const h8*)(uqkg + fo * 136 + g * 8); };
  auto lda = [&](int o) { int fo = o / 17, g = o - fo * 17;
                          return *(const h8*)(abg + fo * 272 + g * 16); };
  auto ldb = [&](int o) { int fo = o / 17, g = o - fo * 17;
                          return *(const h8*)(abg + fo * 272 + g * 16 + 8); };
  h8 qU0 = ldu(t5),       qA0 = lda(t5),       qB0 = ldb(t5);
  h8 qU1 = ldu(t5 + 256), qA1 = lda(t5 + 256), qB1 = ldb(t5 + 256);
  h8 qU2 = ldu(t5 + 512), qA2 = lda(t5 + 512), qB2 = ldb(t5 + 512);
  h8 qU3 = ldu(t5 + 768), qA3 = lda(t5 + 768), qB3 = ldb(t5 + 768);
  h8 qUt = {}, qAt = {}, qBt = {};
  if (t5 < 64) { qUt = ldu(1024 + t5); qAt = lda(1024 + t5); qBt = ldb(1024 + t5); }
  auto ldvu = [&](int o) { int t = o >> 3, vf = o & 7;
                           return *(const h8*)(uvg + t * 64 + vf * 8); };
  auto ldva = [&](int o) { int t = o >> 3, vf = o & 7;
                           return *(const h8*)(ABv + t * 128 + vf * 8); };
  auto ldvb = [&](int o) { int t = o >> 3, vf = o & 7;
                           return *(const h8*)(ABv + t * 128 + 64 + vf * 8); };
  h8 vU0 = ldvu(tid),       vA0 = ldva(tid),       vB0 = ldvb(tid);
  h8 vU1 = ldvu(tid + 512), vA1 = ldva(tid + 512), vB1 = ldvb(tid + 512);
  h8 vUt = {}, vAt = {}, vBt = {};
  if (tid < 16) { vUt = ldvu(1024 + tid); vAt = ldva(1024 + tid); vBt = ldvb(1024 + tid); }

  __syncthreads();   // coeffs slots 0/1, w129h, tails, S1l ready

  // regen one q/k octet (register operands) into buffer with coeff slot sl
  auto genqk = [&](int o, h8 uu, h8 aa, h8 bb, int sl, unsigned short* dstb) {
    int fo = o / 17, g = o - fo * 17;
    _Float16 m   = __builtin_bit_cast(_Float16, mrowB[sl][fo]);
    _Float16 inv = __builtin_bit_cast(_Float16, irowB[sl][fo]);
    _Float16 c   = __builtin_bit_cast(_Float16, crowB[sl][fo]);
    h8 ww = *(const h8*)(&w129h[isK][g * 8]);
    h8 res = (uu + c * ww - m * aa) * inv + bb;
    *(h8*)(dstb + fo * 168 + g * 8) = res;
  };
  auto genv = [&](int o, h8 uu, h8 aa, h8 bb, int sl, unsigned short* vbase) {
    int t = o >> 3, vf = o & 7;
    _Float16 wv = __builtin_bit_cast(_Float16, w129h[2][t]);
    h8 mv = *(const h8*)(&mrowB[sl][vf * 8]);
    h8 iv = *(const h8*)(&irowB[sl][vf * 8]);
    h8 cv = *(const h8*)(&crowB[sl][vf * 8]);
    h8 res = (uu + cv * wv - mv * aa) * iv + bb;
    *(h8*)(vbase + t * 72 + vf * 8) = res;
  };
  auto regen_all = [&](int bufi, int sl) {
    unsigned short* dq = isK ? kb[bufi] : qb[bufi];
    genqk(t5,       qU0, qA0, qB0, sl, dq);
    genqk(t5 + 256, qU1, qA1, qB1, sl, dq);
    genqk(t5 + 512, qU2, qA2, qB2, sl, dq);
    genqk(t5 + 768, qU3, qA3, qB3, sl, dq);
    if (t5 < 64) genqk(1024 + t5, qUt, qAt, qBt, sl, dq);
    genv(tid,       vU0, vA0, vB0, sl, vT[bufi]);
    genv(tid + 512, vU1, vA1, vB1, sl, vT[bufi]);
    if (tid < 16) genv(1024 + tid, vUt, vAt, vBt, sl, vT[bufi]);
  };

  // ---- prologue: regen n=0 into buf[0] (slot 0) ----
  regen_all(0, 0);
  __syncthreads();

  // ---- main loop: ONE barrier per n ----
  for (int n = 0; n < 64; ++n) {
    int p = n & 1;
    if (n > 0 && tid == 0)
      out[b * 64 + n - 1] = redbuf[1 - p][0] + redbuf[1 - p][1]
                          + redbuf[1 - p][2] + redbuf[1 - p][3] + ccv;
    // regen n+1 into buf[1-p] (all waves; independent of compute below)
    if (n < 63) regen_all(1 - p, 1 - p);

    if (w < 4) {
      // ======== COMPUTE n from buf[p] (in-wave) ========
      const unsigned short* qbp = qb[p];
      const unsigned short* kbp = kb[p];
      const unsigned short* vtp = vT[p];
      f32x4 sacc[4] = {};
      {
        const unsigned short* qrow = &qbp[(w * 16 + l15) * 168 + l4 * 8];
#pragma unroll
        for (int kk = 0; kk < 5; ++kk) {
          h8 avv = *(const h8*)&qrow[kk * 32];
#pragma unroll
          for (int cf = 0; cf < 4; ++cf) {
            h8 bvv = *(const h8*)&kbp[(cf * 16 + l15) * 168 + l4 * 8 + kk * 32];
            sacc[cf] = __builtin_amdgcn_mfma_f32_16x16x32_f16(avv, bvv, sacc[cf], 0, 0, 0);
          }
        }
      }
      // max-free in-wave softmax (|sim*INVS| << 88; shift-invariant)
      float prob[4][4];
#pragma unroll
      for (int rr = 0; rr < 4; ++rr) {
        float ssum = 0.f;
#pragma unroll
        for (int cf = 0; cf < 4; ++cf) {
          float e = __expf(sacc[cf][rr] * INVS);
          prob[cf][rr] = e;
          ssum += e;
        }
#pragma unroll
        for (int msk = 1; msk <= 8; msk <<= 1) ssum += __shfl_xor(ssum, msk, 64);
        float is = 1.f / ssum;
#pragma unroll
        for (int cf = 0; cf < 4; ++cf) prob[cf][rr] *= is;
      }
#pragma unroll
      for (int cf = 0; cf < 4; ++cf) {
        unsigned int p01 = pkh(prob[cf][0], prob[cf][1]);
        unsigned int p23 = pkh(prob[cf][2], prob[cf][3]);
        int base = (w * 16 + l4 * 4) * 72 + cf * 16 + l15;
        pb[base]       = (unsigned short)p01;
        pb[base + 72]  = (unsigned short)(p01 >> 16);
        pb[base + 144] = (unsigned short)p23;
        pb[base + 216] = (unsigned short)(p23 >> 16);
      }
      // pb rows produced and consumed by the same wave (R1-proven).

      // PV: all 9 s-tiles in-wave
      f32x4 ao[9] = {};
      {
        const unsigned short* prow = &pb[(w * 16 + l15) * 72 + l4 * 8];
#pragma unroll
        for (int kk = 0; kk < 2; ++kk) {
          h8 avv = *(const h8*)&prow[kk * 32];
#pragma unroll
          for (int sf = 0; sf < 9; ++sf) {
            h8 bvv = *(const h8*)&vtp[(sf * 16 + l15) * 72 + l4 * 8 + kk * 32];
            ao[sf] = __builtin_amdgcn_mfma_f32_16x16x32_f16(avv, bvv, ao[sf], 0, 0, 0);
          }
        }
      }
      // in-wave stats + projection (register AW; pads are zero)
      float csum = 0.f;
#pragma unroll
      for (int rr = 0; rr < 4; ++rr) {
        float s1 = 0.f, s2 = 0.f, sdt = 0.f;
#pragma unroll
        for (int sf = 0; sf < 9; ++sf) {
          float v = ao[sf][rr];
          s1 += v; s2 += v * v; sdt += v * awr[sf][rr];
        }
#pragma unroll
        for (int msk = 1; msk <= 8; msk <<= 1) {
          s1 += __shfl_xor(s1, msk, 64);
          s2 += __shfl_xor(s2, msk, 64);
          sdt += __shfl_xor(sdt, msk, 64);
        }
        float mz  = 2.f * s1 * (1.f / 130.f);
        float ez2 = 4.f * s2 * (1.f / 130.f);
        float sg  = sqrtf(fmaxf(ez2 - mz * mz, 0.f));
        float i2  = 1.f / (sg + EPSF);
        csum += (2.f * sdt - mz * pawr[rr]) * i2;
      }
      csum += __shfl_xor(csum, 16, 64);
      csum += __shfl_xor(csum, 32, 64);
      if (l == 0) redbuf[p][w] = csum;
    } else if (w == 4 && n < 62) {
      // coeffs for n+2 -> slot p (regen this phase reads slot 1-p)
      int ff = l;
      float a  = h2[((size_t)(b * 64 + n + 2)) * 64 + ff];
      float m  = (S1l[ff] + a) * (1.f / 130.f);
      float e2 = (S2l[ff] + a * a) * (1.f / 130.f);
      float sd = sqrtf(fmaxf(e2 - m * m, 0.f));
      mrowB[p][ff] = f2h(m);
      irowB[p][ff] = f2h(1.f / (sd + EPSF));
      crowB[p][ff] = f2h(ael[ff] * a);
    }
    __syncthreads();
  }
  if (tid == 0)
    out[b * 64 + 63] = redbuf[1][0] + redbuf[1][1] + redbuf[1][2] + redbuf[1][3] + ccv;
}

// ---------------- host launch ----------------
extern "C" void kernel_launch(void* const* d_in, const int* in_sizes, int n_in,
                              void* d_out, int out_size, void* d_ws, size_t ws_size,
                              hipStream_t stream) {
  const float* sp     = (const float*)d_in[0];
  const float* h1     = (const float*)d_in[1];
  const float* h2     = (const float*)d_in[2];
  const float* Wq     = (const float*)d_in[3];
  const float* bq     = (const float*)d_in[4];
  const float* Wk     = (const float*)d_in[5];
  const float* bk     = (const float*)d_in[6];
  const float* Wv     = (const float*)d_in[7];
  const float* bv     = (const float*)d_in[8];
  const float* alpha1 = (const float*)d_in[9];
  const float* beta1  = (const float*)d_in[10];
  const float* alpha2 = (const float*)d_in[11];
  const float* beta2  = (const float*)d_in[12];
  const float* Wlin   = (const float*)d_in[13];
  const float* blin   = (const float*)d_in[14];
  float* out = (float*)d_out;

  unsigned short* UqkB = (unsigned short*)d_ws;     // 256*2*64*136 = 4,456,448
  unsigned short* UvB  = UqkB + 4456448;            // 256*136*64   = 2,228,224
  unsigned short* ABqk = UvB + 2228224;             // 2*64*272     = 34,816
  unsigned short* ABv  = ABqk + 34816;              // 136*128      = 17,408
  unsigned short* AWt  = ABv + 17408;               // 144*72       = 10,368
  float* S1g = (float*)(AWt + 10368);               // 16384
  float* S2g = S1g + 16384;                         // 16384
  float* Paw = S2g + 16384;                         // 64
  float* Ccw = Paw + 64;                            // 1   -> total ~13.6 MB

  k01<<<dim3(263), dim3(256), 0, stream>>>(h1, h2, sp,
                                           alpha1, beta1, alpha2, beta2,
                                           Wq, bq, Wk, bk, Wv, bv, Wlin, blin,
                                           UqkB, UvB, ABqk, ABv, AWt, Paw, Ccw,
                                           S1g, S2g);
  k2<<<dim3(256), dim3(512), 0, stream>>>(h2, alpha1, UqkB, UvB, ABqk, ABv, AWt,
                                          S1g, S2g, Paw, Ccw,
                                          Wq, Wk, Wv, out);
}